// Round 9
// baseline (266.662 us; speedup 1.0000x reference)
//
#include <hip/hip_runtime.h>

#define EPS 1e-5f

typedef __attribute__((ext_vector_type(8))) short bf16x8;
typedef __attribute__((ext_vector_type(4))) short short4v;
typedef __attribute__((ext_vector_type(4))) float f32x4;

__device__ __forceinline__ float fexp(float x){ return __builtin_amdgcn_exp2f(x*1.4426950408889634f); }
__device__ __forceinline__ float frcp(float x){ return __builtin_amdgcn_rcpf(x); }
__device__ __forceinline__ float fsig(float x){ return frcp(1.0f + fexp(-x)); }
__device__ __forceinline__ float ftanh(float x){ return 1.0f - 2.0f*frcp(fexp(2.0f*x) + 1.0f); }

__device__ __forceinline__ short bfhi(float v){ return (short)(__float_as_uint(v) >> 16); }
__device__ __forceinline__ float bfhif(float v){ return __uint_as_float(__float_as_uint(v) & 0xFFFF0000u); }

// ws float layout:
//   [0]            mean_x
//   [16..1040)     mean partials
//   [1056..1312)   add0 ; [1312..1568) add1
// shorts region SB = (short*)(ws + 2048):
//  tier-1 (ws_size >= WS_NEED_FULL): per layer l at SB + l*32768:
//     2048 slots x 16 shorts: [0..8) = whi frag, [8..16) = wlo frag
//     slot = (mt*2+ks)*64 + lane ; g = mt*16+(lane&15), k = ks*32+(lane>>4)*8+j
//  tier-2 (ws_size >= WS_NEED_MIN): SB[0..16384)=wlo0, SB[16384..32768)=wlo1
#define WS_NEED_MIN  (2048*4 + 2*16384*2)    // 73728
#define WS_NEED_FULL (2048*4 + 2*32768*2)    // 139264

// ---------------- mean(x) reduction (deterministic, 2-stage) ----------------
__global__ void mean_part(const float* __restrict__ x, int P, float* __restrict__ part)
{
    __shared__ float red[256];
    int tid = blockIdx.x*256 + threadIdx.x;
    float s = 0.0f;
    for (int i = tid; i < P; i += 256*1024) s += x[i];
    red[threadIdx.x] = s; __syncthreads();
    for (int w = 128; w > 0; w >>= 1){
        if (threadIdx.x < w) red[threadIdx.x] += red[threadIdx.x + w];
        __syncthreads();
    }
    if (threadIdx.x == 0) part[blockIdx.x] = red[0];
}

__global__ void mean_fin(const float* __restrict__ part, float* __restrict__ ws, int P)
{
    __shared__ float red[1024];
    int t = threadIdx.x;
    red[t] = part[t]; __syncthreads();
    for (int w = 512; w > 0; w >>= 1){
        if (t < w) red[t] += red[t + w];
        __syncthreads();
    }
    if (t == 0) ws[0] = red[0] / (float)P;
}

// ---------------- add-vector precompute: add = LN(bh,gh,bgh) + bgi ----------------
__global__ void precomp_add(
    const float* __restrict__ bh0, const float* __restrict__ gh0,
    const float* __restrict__ bgh0, const float* __restrict__ bgi0,
    const float* __restrict__ bh1, const float* __restrict__ gh1,
    const float* __restrict__ bgh1, const float* __restrict__ bgi1,
    float* __restrict__ ws)
{
    const int l = blockIdx.x;
    const float* bh  = l ? bh1  : bh0;
    const float* gh  = l ? gh1  : gh0;
    const float* bgh = l ? bgh1 : bgh0;
    const float* bgi = l ? bgi1 : bgi0;
    float* add = ws + 1056 + l*256;
    int t = threadIdx.x;

    __shared__ float r1[256], r2[256];
    float v = bh[t];
    r1[t] = v; r2[t] = v*v; __syncthreads();
    for (int w = 128; w > 0; w >>= 1){
        if (t < w){ r1[t] += r1[t+w]; r2[t] += r2[t+w]; }
        __syncthreads();
    }
    float m   = r1[0] * (1.0f/256.0f);
    float var = (r2[0] - 256.0f*m*m) * (1.0f/255.0f);
    float s   = sqrtf(fmaxf(var, 0.0f));
    float c   = (v - m) * frcp(s + EPS) * gh[t] + bgh[t];
    add[t] = c + bgi[t];
}

// ---------------- tier-1: full hi|lo fragment images (interleaved 32B slots) ----------------
__global__ void precomp_wfrag(const float* __restrict__ Wi0, const float* __restrict__ Wi1,
                              float* __restrict__ ws)
{
    const int l = blockIdx.x;
    const float* Wi = l ? Wi1 : Wi0;
    short* wf = (short*)(ws + 2048) + l*32768;
    int t = threadIdx.x;
    for (int i = 0; i < 8; ++i){                // 2048 slots
        int slot = i*256 + t;
        int lane = slot & 63, mtks = slot >> 6; // 0..31
        int g  = ((mtks >> 1) << 4) + (lane & 15);
        int k  = ((mtks & 1) << 5) + ((lane >> 4) << 3);
        short hi8[8], lo8[8];
        #pragma unroll
        for (int j = 0; j < 8; ++j){
            float w = Wi[(g << 6) + k + j];
            hi8[j] = bfhi(w);
            lo8[j] = bfhi(w - bfhif(w));
        }
        short* d = wf + slot*16;
        *(short4v*)(d     ) = short4v{ hi8[0], hi8[1], hi8[2], hi8[3] };
        *(short4v*)(d +  4) = short4v{ hi8[4], hi8[5], hi8[6], hi8[7] };
        *(short4v*)(d +  8) = short4v{ lo8[0], lo8[1], lo8[2], lo8[3] };
        *(short4v*)(d + 12) = short4v{ lo8[4], lo8[5], lo8[6], lo8[7] };
    }
}

// ---------------- tier-2: wlo-only fragment images ----------------
__global__ void precomp_wlo(const float* __restrict__ Wi0, const float* __restrict__ Wi1,
                            float* __restrict__ ws)
{
    const int l = blockIdx.x;
    const float* Wi = l ? Wi1 : Wi0;
    short* wlos = (short*)(ws + 2048) + l*16384;
    int t = threadIdx.x;
    for (int i = 0; i < 8; ++i){
        int slot = i*256 + t;
        int lane = slot & 63, mtks = slot >> 6;
        int mt = mtks >> 1, ks = mtks & 1;
        int g  = (mt << 4) + (lane & 15);
        int k  = (ks << 5) + ((lane >> 4) << 3);
        short tmp[8];
        #pragma unroll
        for (int j = 0; j < 8; ++j){
            float w = Wi[(g << 6) + k + j];
            tmp[j] = bfhi(w - bfhif(w));
        }
        *(short4v*)(wlos + slot*8)     = short4v{ tmp[0], tmp[1], tmp[2], tmp[3] };
        *(short4v*)(wlos + slot*8 + 4) = short4v{ tmp[4], tmp[5], tmp[6], tmp[7] };
    }
}

struct LayerParams { const float *bi, *gi, *addv, *gc, *bc; };

// ---------------- tier-1 kernel: barrier-free, weights fully streamed ----------------
// 256 threads = 4 waves; wave = 16 rows, fully independent (hb is per-wave,
// no __syncthreads anywhere). LDS = 16 KB. launch_bounds(256,3): cap ~170 regs.
__global__ __launch_bounds__(256, 3) void fwd_nobar(
    const float* __restrict__ x,
    const float* __restrict__ W1, const float* __restrict__ b1,
    const float* __restrict__ g1, const float* __restrict__ be1,
    const float* __restrict__ bi0, const float* __restrict__ gi0,
    const float* __restrict__ gc0, const float* __restrict__ bc0,
    const float* __restrict__ bi1, const float* __restrict__ gi1,
    const float* __restrict__ gc1, const float* __restrict__ bc1,
    const float* __restrict__ Wo, const float* __restrict__ bo,
    const float* __restrict__ ws, float* __restrict__ out, int P)
{
    __shared__ short hb[8192];    // [wave(4)][part(2)][row16][cell64] swizzled (16 KB)

    const int tid  = threadIdx.x;
    const int wid  = tid >> 6;
    const int lane = tid & 63;
    const int c16  = lane & 15;
    const int q    = lane >> 4;
    const int row  = blockIdx.x*64 + wid*16 + c16;
    short* hbw = hb + wid*2048;
    const int swz = (c16 & 7) << 3;
    const short* SB = (const short*)(ws + 2048);

    float xv = 0.0f;
    if (row < P) xv = x[row];
    else if (row == P) xv = ws[0];

    // ---- input layer: h = tanh(LN64(x*W1 + b1)); write per-wave hb ----
    {
        float h[16];
        float sm = 0.f, sq = 0.f;
        #pragma unroll
        for (int mt4 = 0; mt4 < 4; ++mt4){
            const f32x4 w14 = *(const f32x4*)(W1 + mt4*16 + (q << 2));
            const f32x4 b14 = *(const f32x4*)(b1 + mt4*16 + (q << 2));
            #pragma unroll
            for (int r = 0; r < 4; ++r){
                float v = xv*w14[r] + b14[r];
                h[mt4*4+r] = v; sm += v; sq += v*v;
            }
        }
        sm += __shfl_xor(sm, 16); sm += __shfl_xor(sm, 32);
        sq += __shfl_xor(sq, 16); sq += __shfl_xor(sq, 32);
        const float m   = sm * (1.0f/64.0f);
        const float var = (sq - 64.0f*m*m) * (1.0f/63.0f);
        const float inv = frcp(sqrtf(fmaxf(var, 0.0f)) + EPS);
        #pragma unroll
        for (int mt4 = 0; mt4 < 4; ++mt4){
            const f32x4 g14  = *(const f32x4*)(g1  + mt4*16 + (q << 2));
            const f32x4 be14 = *(const f32x4*)(be1 + mt4*16 + (q << 2));
            #pragma unroll
            for (int r = 0; r < 4; ++r)
                h[mt4*4+r] = ftanh((h[mt4*4+r]-m)*inv*g14[r] + be14[r]);
        }
        #pragma unroll
        for (int mt4 = 0; mt4 < 4; ++mt4){
            int si = ((c16 << 6) + mt4*16 + (q << 2)) ^ swz;
            float a = h[mt4*4+0], b = h[mt4*4+1], c = h[mt4*4+2], d = h[mt4*4+3];
            *(short4v*)(hbw + si)        = short4v{ bfhi(a), bfhi(b), bfhi(c), bfhi(d) };
            *(short4v*)(hbw + 1024 + si) = short4v{ bfhi(a-bfhif(a)), bfhi(b-bfhif(b)),
                                                    bfhi(c-bfhif(c)), bfhi(d-bfhif(d)) };
        }
    }
    // no barrier: hb region is private to this wave

    f32x4 acc[16];     // gate accumulators; after do_layer, acc[0..3] = h-out

    auto do_layer = [&](LayerParams p, const short* __restrict__ wfrag, bool writeback){
        bf16x8 bhh[2], bhl[2];
        #pragma unroll
        for (int ks = 0; ks < 2; ++ks){
            int si = ((c16 << 6) + ks*32 + (q << 3)) ^ swz;
            bhh[ks] = *(const bf16x8*)(hbw + si);
            bhl[ks] = *(const bf16x8*)(hbw + 1024 + si);
        }
        #pragma unroll
        for (int mt = 0; mt < 16; ++mt)
            acc[mt] = *(const f32x4*)(p.bi + mt*16 + (q << 2));
        #pragma unroll
        for (int mt = 0; mt < 16; ++mt){
            #pragma unroll
            for (int ks = 0; ks < 2; ++ks){
                int off = (((mt << 1) + ks) << 10) + (lane << 4);   // slot*16 shorts
                bf16x8 whi = *(const bf16x8*)(wfrag + off);
                bf16x8 wlo = *(const bf16x8*)(wfrag + off + 8);
                acc[mt] = __builtin_amdgcn_mfma_f32_16x16x32_bf16(whi, bhh[ks], acc[mt], 0, 0, 0);
                acc[mt] = __builtin_amdgcn_mfma_f32_16x16x32_bf16(whi, bhl[ks], acc[mt], 0, 0, 0);
                acc[mt] = __builtin_amdgcn_mfma_f32_16x16x32_bf16(wlo, bhh[ks], acc[mt], 0, 0, 0);
            }
        }
        // LN256 stats
        float sm = 0.f, sq = 0.f;
        #pragma unroll
        for (int mt = 0; mt < 16; ++mt){
            #pragma unroll
            for (int r = 0; r < 4; ++r){ float v = acc[mt][r]; sm += v; sq += v*v; }
        }
        sm += __shfl_xor(sm, 16); sm += __shfl_xor(sm, 32);
        sq += __shfl_xor(sq, 16); sq += __shfl_xor(sq, 32);
        const float m   = sm * (1.0f/256.0f);
        const float var = (sq - 256.0f*m*m) * (1.0f/255.0f);
        const float inv = frcp(sqrtf(fmaxf(var, 0.0f)) + EPS);

        // gates in place: acc[mt4] <- cx = sig(i)*tanh(g); acc[mt4+8] <- o
        #pragma unroll
        for (int mt4 = 0; mt4 < 4; ++mt4){
            const f32x4 giI = *(const f32x4*)(p.gi   +       mt4*16 + (q << 2));
            const f32x4 giO = *(const f32x4*)(p.gi   + 128 + mt4*16 + (q << 2));
            const f32x4 giG = *(const f32x4*)(p.gi   + 192 + mt4*16 + (q << 2));
            const f32x4 adI = *(const f32x4*)(p.addv +       mt4*16 + (q << 2));
            const f32x4 adO = *(const f32x4*)(p.addv + 128 + mt4*16 + (q << 2));
            const f32x4 adG = *(const f32x4*)(p.addv + 192 + mt4*16 + (q << 2));
            #pragma unroll
            for (int r = 0; r < 4; ++r){
                const float i_ = (acc[mt4   ][r]-m)*inv*giI[r] + adI[r];
                const float o_ = (acc[mt4+ 8][r]-m)*inv*giO[r] + adO[r];
                const float g_ = (acc[mt4+12][r]-m)*inv*giG[r] + adG[r];
                acc[mt4   ][r] = fsig(i_) * ftanh(g_);
                acc[mt4+ 8][r] = o_;
            }
        }
        // LN64 over cx (acc[0..3]), then acc[mt4] <- sig(oo)*tanh(LN(cx))
        float s2 = 0.f, q2 = 0.f;
        #pragma unroll
        for (int mt4 = 0; mt4 < 4; ++mt4){
            #pragma unroll
            for (int r = 0; r < 4; ++r){ float v = acc[mt4][r]; s2 += v; q2 += v*v; }
        }
        s2 += __shfl_xor(s2, 16); s2 += __shfl_xor(s2, 32);
        q2 += __shfl_xor(q2, 16); q2 += __shfl_xor(q2, 32);
        const float mc = s2 * (1.0f/64.0f);
        const float vc = (q2 - 64.0f*mc*mc) * (1.0f/63.0f);
        const float ic = frcp(sqrtf(fmaxf(vc, 0.0f)) + EPS);
        #pragma unroll
        for (int mt4 = 0; mt4 < 4; ++mt4){
            const f32x4 gc4 = *(const f32x4*)(p.gc + mt4*16 + (q << 2));
            const f32x4 bc4 = *(const f32x4*)(p.bc + mt4*16 + (q << 2));
            #pragma unroll
            for (int r = 0; r < 4; ++r)
                acc[mt4][r] = fsig(acc[mt4+8][r]) * ftanh((acc[mt4][r]-mc)*ic*gc4[r] + bc4[r]);
        }
        if (writeback){
            #pragma unroll
            for (int mt4 = 0; mt4 < 4; ++mt4){
                int si = ((c16 << 6) + mt4*16 + (q << 2)) ^ swz;
                float a = acc[mt4][0], b = acc[mt4][1], c = acc[mt4][2], d = acc[mt4][3];
                *(short4v*)(hbw + si)        = short4v{ bfhi(a), bfhi(b), bfhi(c), bfhi(d) };
                *(short4v*)(hbw + 1024 + si) = short4v{ bfhi(a-bfhif(a)), bfhi(b-bfhif(b)),
                                                        bfhi(c-bfhif(c)), bfhi(d-bfhif(d)) };
            }
        }
    };

    do_layer({bi0, gi0, ws + 1056, gc0, bc0}, SB,          true);
    do_layer({bi1, gi1, ws + 1312, gc1, bc1}, SB + 32768, false);

    // output: out = h2 . Wo + bo  (h2 in acc[0..3])
    float o = 0.f;
    #pragma unroll
    for (int mt4 = 0; mt4 < 4; ++mt4){
        const f32x4 wo4 = *(const f32x4*)(Wo + mt4*16 + (q << 2));
        #pragma unroll
        for (int r = 0; r < 4; ++r) o += acc[mt4][r]*wo4[r];
    }
    o += __shfl_xor(o, 16); o += __shfl_xor(o, 32);
    if (q == 0 && row <= P) out[row] = o + bo[0];
}

// ---------------- tier-2 fallback: round-8 proven kernel ----------------
__global__ __launch_bounds__(256, 3) void fwd_stream(
    const float* __restrict__ x,
    const float* __restrict__ W1, const float* __restrict__ b1,
    const float* __restrict__ g1, const float* __restrict__ be1,
    const float* __restrict__ Wi0, const float* __restrict__ bi0,
    const float* __restrict__ gi0, const float* __restrict__ gc0, const float* __restrict__ bc0,
    const float* __restrict__ Wi1, const float* __restrict__ bi1,
    const float* __restrict__ gi1, const float* __restrict__ gc1, const float* __restrict__ bc1,
    const float* __restrict__ Wo, const float* __restrict__ bo,
    const float* __restrict__ ws, float* __restrict__ out, int P)
{
    __shared__ short wl[16384];
    __shared__ short hb[8192];

    const int tid  = threadIdx.x;
    const int wid  = tid >> 6;
    const int lane = tid & 63;
    const int c16  = lane & 15;
    const int q    = lane >> 4;
    const int row  = blockIdx.x*64 + wid*16 + c16;
    short* hbw = hb + wid*2048;
    const int swz = (c16 & 7) << 3;
    const short* SB = (const short*)(ws + 2048);

    auto stage_hi = [&](const float* __restrict__ W){
        #pragma unroll
        for (int i = 0; i < 16; ++i){
            int idx = i*256 + tid;
            int g = idx >> 4, k0 = (idx & 15) << 2;
            f32x4 w4 = *(const f32x4*)(W + (idx << 2));
            int si = ((g << 6) + k0) ^ ((g & 7) << 3);
            *(short4v*)(wl + si) = short4v{ bfhi(w4[0]), bfhi(w4[1]), bfhi(w4[2]), bfhi(w4[3]) };
        }
    };

    stage_hi(Wi0);

    float xv = 0.0f;
    if (row < P) xv = x[row];
    else if (row == P) xv = ws[0];

    {
        float h[16];
        float sm = 0.f, sq = 0.f;
        #pragma unroll
        for (int mt4 = 0; mt4 < 4; ++mt4){
            const f32x4 w14 = *(const f32x4*)(W1 + mt4*16 + (q << 2));
            const f32x4 b14 = *(const f32x4*)(b1 + mt4*16 + (q << 2));
            #pragma unroll
            for (int r = 0; r < 4; ++r){
                float v = xv*w14[r] + b14[r];
                h[mt4*4+r] = v; sm += v; sq += v*v;
            }
        }
        sm += __shfl_xor(sm, 16); sm += __shfl_xor(sm, 32);
        sq += __shfl_xor(sq, 16); sq += __shfl_xor(sq, 32);
        const float m   = sm * (1.0f/64.0f);
        const float var = (sq - 64.0f*m*m) * (1.0f/63.0f);
        const float inv = frcp(sqrtf(fmaxf(var, 0.0f)) + EPS);
        #pragma unroll
        for (int mt4 = 0; mt4 < 4; ++mt4){
            const f32x4 g14  = *(const f32x4*)(g1  + mt4*16 + (q << 2));
            const f32x4 be14 = *(const f32x4*)(be1 + mt4*16 + (q << 2));
            #pragma unroll
            for (int r = 0; r < 4; ++r)
                h[mt4*4+r] = ftanh((h[mt4*4+r]-m)*inv*g14[r] + be14[r]);
        }
        #pragma unroll
        for (int mt4 = 0; mt4 < 4; ++mt4){
            int si = ((c16 << 6) + mt4*16 + (q << 2)) ^ swz;
            float a = h[mt4*4+0], b = h[mt4*4+1], c = h[mt4*4+2], d = h[mt4*4+3];
            *(short4v*)(hbw + si)        = short4v{ bfhi(a), bfhi(b), bfhi(c), bfhi(d) };
            *(short4v*)(hbw + 1024 + si) = short4v{ bfhi(a-bfhif(a)), bfhi(b-bfhif(b)),
                                                    bfhi(c-bfhif(c)), bfhi(d-bfhif(d)) };
        }
    }
    __syncthreads();

    f32x4 acc[16];

    auto do_layer = [&](LayerParams p, const short* __restrict__ wlofrag, bool writeback){
        bf16x8 bhh[2], bhl[2];
        #pragma unroll
        for (int ks = 0; ks < 2; ++ks){
            int si = ((c16 << 6) + ks*32 + (q << 3)) ^ swz;
            bhh[ks] = *(const bf16x8*)(hbw + si);
            bhl[ks] = *(const bf16x8*)(hbw + 1024 + si);
        }
        #pragma unroll
        for (int mt = 0; mt < 16; ++mt)
            acc[mt] = *(const f32x4*)(p.bi + mt*16 + (q << 2));
        #pragma unroll
        for (int mt = 0; mt < 16; ++mt){
            #pragma unroll
            for (int ks = 0; ks < 2; ++ks){
                int si = ((((mt << 4) + c16) << 6) + ks*32 + (q << 3)) ^ swz;
                bf16x8 whi = *(const bf16x8*)(wl + si);
                bf16x8 wlo = *(const bf16x8*)(wlofrag + ((mt*2 + ks) << 9) + (lane << 3));
                acc[mt] = __builtin_amdgcn_mfma_f32_16x16x32_bf16(whi, bhh[ks], acc[mt], 0, 0, 0);
                acc[mt] = __builtin_amdgcn_mfma_f32_16x16x32_bf16(whi, bhl[ks], acc[mt], 0, 0, 0);
                acc[mt] = __builtin_amdgcn_mfma_f32_16x16x32_bf16(wlo, bhh[ks], acc[mt], 0, 0, 0);
            }
        }
        float sm = 0.f, sq = 0.f;
        #pragma unroll
        for (int mt = 0; mt < 16; ++mt){
            #pragma unroll
            for (int r = 0; r < 4; ++r){ float v = acc[mt][r]; sm += v; sq += v*v; }
        }
        sm += __shfl_xor(sm, 16); sm += __shfl_xor(sm, 32);
        sq += __shfl_xor(sq, 16); sq += __shfl_xor(sq, 32);
        const float m   = sm * (1.0f/256.0f);
        const float var = (sq - 256.0f*m*m) * (1.0f/255.0f);
        const float inv = frcp(sqrtf(fmaxf(var, 0.0f)) + EPS);

        #pragma unroll
        for (int mt4 = 0; mt4 < 4; ++mt4){
            const f32x4 giI = *(const f32x4*)(p.gi   +       mt4*16 + (q << 2));
            const f32x4 giO = *(const f32x4*)(p.gi   + 128 + mt4*16 + (q << 2));
            const f32x4 giG = *(const f32x4*)(p.gi   + 192 + mt4*16 + (q << 2));
            const f32x4 adI = *(const f32x4*)(p.addv +       mt4*16 + (q << 2));
            const f32x4 adO = *(const f32x4*)(p.addv + 128 + mt4*16 + (q << 2));
            const f32x4 adG = *(const f32x4*)(p.addv + 192 + mt4*16 + (q << 2));
            #pragma unroll
            for (int r = 0; r < 4; ++r){
                const float i_ = (acc[mt4   ][r]-m)*inv*giI[r] + adI[r];
                const float o_ = (acc[mt4+ 8][r]-m)*inv*giO[r] + adO[r];
                const float g_ = (acc[mt4+12][r]-m)*inv*giG[r] + adG[r];
                acc[mt4   ][r] = fsig(i_) * ftanh(g_);
                acc[mt4+ 8][r] = o_;
            }
        }
        float s2 = 0.f, q2 = 0.f;
        #pragma unroll
        for (int mt4 = 0; mt4 < 4; ++mt4){
            #pragma unroll
            for (int r = 0; r < 4; ++r){ float v = acc[mt4][r]; s2 += v; q2 += v*v; }
        }
        s2 += __shfl_xor(s2, 16); s2 += __shfl_xor(s2, 32);
        q2 += __shfl_xor(q2, 16); q2 += __shfl_xor(q2, 32);
        const float mc = s2 * (1.0f/64.0f);
        const float vc = (q2 - 64.0f*mc*mc) * (1.0f/63.0f);
        const float ic = frcp(sqrtf(fmaxf(vc, 0.0f)) + EPS);
        #pragma unroll
        for (int mt4 = 0; mt4 < 4; ++mt4){
            const f32x4 gc4 = *(const f32x4*)(p.gc + mt4*16 + (q << 2));
            const f32x4 bc4 = *(const f32x4*)(p.bc + mt4*16 + (q << 2));
            #pragma unroll
            for (int r = 0; r < 4; ++r)
                acc[mt4][r] = fsig(acc[mt4+8][r]) * ftanh((acc[mt4][r]-mc)*ic*gc4[r] + bc4[r]);
        }
        if (writeback){
            #pragma unroll
            for (int mt4 = 0; mt4 < 4; ++mt4){
                int si = ((c16 << 6) + mt4*16 + (q << 2)) ^ swz;
                float a = acc[mt4][0], b = acc[mt4][1], c = acc[mt4][2], d = acc[mt4][3];
                *(short4v*)(hbw + si)        = short4v{ bfhi(a), bfhi(b), bfhi(c), bfhi(d) };
                *(short4v*)(hbw + 1024 + si) = short4v{ bfhi(a-bfhif(a)), bfhi(b-bfhif(b)),
                                                        bfhi(c-bfhif(c)), bfhi(d-bfhif(d)) };
            }
        }
    };

    do_layer({bi0, gi0, ws + 1056, gc0, bc0}, SB,          true);
    __syncthreads();
    stage_hi(Wi1);
    __syncthreads();
    do_layer({bi1, gi1, ws + 1312, gc1, bc1}, SB + 16384, false);

    float o = 0.f;
    #pragma unroll
    for (int mt4 = 0; mt4 < 4; ++mt4){
        const f32x4 wo4 = *(const f32x4*)(Wo + mt4*16 + (q << 2));
        #pragma unroll
        for (int r = 0; r < 4; ++r) o += acc[mt4][r]*wo4[r];
    }
    o += __shfl_xor(o, 16); o += __shfl_xor(o, 32);
    if (q == 0 && row <= P) out[row] = o + bo[0];
}

extern "C" void kernel_launch(void* const* d_in, const int* in_sizes, int n_in,
                              void* d_out, int out_size, void* d_ws, size_t ws_size,
                              hipStream_t stream)
{
    (void)n_in; (void)out_size;
    const float* x     = (const float*)d_in[0];
    const float* W1    = (const float*)d_in[1];
    const float* b1    = (const float*)d_in[2];
    const float* g1    = (const float*)d_in[3];
    const float* be1   = (const float*)d_in[4];
    const float* l0_Wi = (const float*)d_in[5];
    const float* l0_bi = (const float*)d_in[6];
    const float* l0_bh = (const float*)d_in[8];
    const float* l0_gi = (const float*)d_in[9];
    const float* l0_bgi= (const float*)d_in[10];
    const float* l0_gh = (const float*)d_in[11];
    const float* l0_bgh= (const float*)d_in[12];
    const float* l0_gc = (const float*)d_in[13];
    const float* l0_bc = (const float*)d_in[14];
    const float* l1_Wi = (const float*)d_in[15];
    const float* l1_bi = (const float*)d_in[16];
    const float* l1_bh = (const float*)d_in[18];
    const float* l1_gi = (const float*)d_in[19];
    const float* l1_bgi= (const float*)d_in[20];
    const float* l1_gh = (const float*)d_in[21];
    const float* l1_bgh= (const float*)d_in[22];
    const float* l1_gc = (const float*)d_in[23];
    const float* l1_bc = (const float*)d_in[24];
    const float* Wo    = (const float*)d_in[25];
    const float* bo    = (const float*)d_in[26];

    int P = in_sizes[0];
    int B = P + 1;
    float* ws  = (float*)d_ws;
    float* out = (float*)d_out;

    mean_part<<<1024, 256, 0, stream>>>(x, P, ws + 16);
    mean_fin<<<1, 1024, 0, stream>>>(ws + 16, ws, P);
    precomp_add<<<2, 256, 0, stream>>>(
        l0_bh, l0_gh, l0_bgh, l0_bgi,
        l1_bh, l1_gh, l1_bgh, l1_bgi, ws);

    if (ws_size >= (size_t)WS_NEED_FULL){
        precomp_wfrag<<<2, 256, 0, stream>>>(l0_Wi, l1_Wi, ws);
        fwd_nobar<<<(B + 63)/64, 256, 0, stream>>>(
            x, W1, b1, g1, be1,
            l0_bi, l0_gi, l0_gc, l0_bc,
            l1_bi, l1_gi, l1_gc, l1_bc,
            Wo, bo, ws, out, P);
    } else {
        precomp_wlo<<<2, 256, 0, stream>>>(l0_Wi, l1_Wi, ws);
        fwd_stream<<<(B + 63)/64, 256, 0, stream>>>(
            x, W1, b1, g1, be1,
            l0_Wi, l0_bi, l0_gi, l0_gc, l0_bc,
            l1_Wi, l1_bi, l1_gi, l1_gc, l1_bc,
            Wo, bo, ws, out, P);
    }
}

// Round 10
// 237.438 us; speedup vs baseline: 1.1231x; 1.1231x over previous
//
#include <hip/hip_runtime.h>

#define EPS 1e-5f

typedef __attribute__((ext_vector_type(8))) short bf16x8;
typedef __attribute__((ext_vector_type(4))) short short4v;
typedef __attribute__((ext_vector_type(4))) float f32x4;

__device__ __forceinline__ float fexp(float x){ return __builtin_amdgcn_exp2f(x*1.4426950408889634f); }
__device__ __forceinline__ float frcp(float x){ return __builtin_amdgcn_rcpf(x); }
__device__ __forceinline__ float fsig(float x){ return frcp(1.0f + fexp(-x)); }
__device__ __forceinline__ float ftanh(float x){ return 1.0f - 2.0f*frcp(fexp(2.0f*x) + 1.0f); }

__device__ __forceinline__ short bfhi(float v){ return (short)(__float_as_uint(v) >> 16); }
__device__ __forceinline__ float bfhif(float v){ return __uint_as_float(__float_as_uint(v) & 0xFFFF0000u); }

// ws float layout:
//   [0]            mean_x
//   [16..1040)     mean partials
//   [1056..1312)   add0 ; [1312..1568) add1
// shorts region SB = (short*)(ws + 2048):
//  tier-1 (ws_size >= WS_NEED_FULL): per layer l at SB + l*32768:
//     2048 slots x 16 shorts: [0..8) = whi frag, [8..16) = wlo frag
//     slot = (mt*2+ks)*64 + lane ; g = mt*16+(lane&15), k = ks*32+(lane>>4)*8+j
//  tier-2 (ws_size >= WS_NEED_MIN): SB[0..16384)=wlo0, SB[16384..32768)=wlo1
#define WS_NEED_MIN  (2048*4 + 2*16384*2)    // 73728
#define WS_NEED_FULL (2048*4 + 2*32768*2)    // 139264

// ---------------- mean(x) reduction (deterministic, 2-stage) ----------------
__global__ void mean_part(const float* __restrict__ x, int P, float* __restrict__ part)
{
    __shared__ float red[256];
    int tid = blockIdx.x*256 + threadIdx.x;
    float s = 0.0f;
    for (int i = tid; i < P; i += 256*1024) s += x[i];
    red[threadIdx.x] = s; __syncthreads();
    for (int w = 128; w > 0; w >>= 1){
        if (threadIdx.x < w) red[threadIdx.x] += red[threadIdx.x + w];
        __syncthreads();
    }
    if (threadIdx.x == 0) part[blockIdx.x] = red[0];
}

__global__ void mean_fin(const float* __restrict__ part, float* __restrict__ ws, int P)
{
    __shared__ float red[1024];
    int t = threadIdx.x;
    red[t] = part[t]; __syncthreads();
    for (int w = 512; w > 0; w >>= 1){
        if (t < w) red[t] += red[t + w];
        __syncthreads();
    }
    if (t == 0) ws[0] = red[0] / (float)P;
}

// ---------------- add-vector precompute: add = LN(bh,gh,bgh) + bgi ----------------
__global__ void precomp_add(
    const float* __restrict__ bh0, const float* __restrict__ gh0,
    const float* __restrict__ bgh0, const float* __restrict__ bgi0,
    const float* __restrict__ bh1, const float* __restrict__ gh1,
    const float* __restrict__ bgh1, const float* __restrict__ bgi1,
    float* __restrict__ ws)
{
    const int l = blockIdx.x;
    const float* bh  = l ? bh1  : bh0;
    const float* gh  = l ? gh1  : gh0;
    const float* bgh = l ? bgh1 : bgh0;
    const float* bgi = l ? bgi1 : bgi0;
    float* add = ws + 1056 + l*256;
    int t = threadIdx.x;

    __shared__ float r1[256], r2[256];
    float v = bh[t];
    r1[t] = v; r2[t] = v*v; __syncthreads();
    for (int w = 128; w > 0; w >>= 1){
        if (t < w){ r1[t] += r1[t+w]; r2[t] += r2[t+w]; }
        __syncthreads();
    }
    float m   = r1[0] * (1.0f/256.0f);
    float var = (r2[0] - 256.0f*m*m) * (1.0f/255.0f);
    float s   = sqrtf(fmaxf(var, 0.0f));
    float c   = (v - m) * frcp(s + EPS) * gh[t] + bgh[t];
    add[t] = c + bgi[t];
}

// ---------------- tier-1: full hi|lo fragment images (interleaved 32B slots) ----------------
__global__ void precomp_wfrag(const float* __restrict__ Wi0, const float* __restrict__ Wi1,
                              float* __restrict__ ws)
{
    const int l = blockIdx.x;
    const float* Wi = l ? Wi1 : Wi0;
    short* wf = (short*)(ws + 2048) + l*32768;
    int t = threadIdx.x;
    for (int i = 0; i < 8; ++i){                // 2048 slots
        int slot = i*256 + t;
        int lane = slot & 63, mtks = slot >> 6; // 0..31
        int g  = ((mtks >> 1) << 4) + (lane & 15);
        int k  = ((mtks & 1) << 5) + ((lane >> 4) << 3);
        short hi8[8], lo8[8];
        #pragma unroll
        for (int j = 0; j < 8; ++j){
            float w = Wi[(g << 6) + k + j];
            hi8[j] = bfhi(w);
            lo8[j] = bfhi(w - bfhif(w));
        }
        short* d = wf + slot*16;
        *(short4v*)(d     ) = short4v{ hi8[0], hi8[1], hi8[2], hi8[3] };
        *(short4v*)(d +  4) = short4v{ hi8[4], hi8[5], hi8[6], hi8[7] };
        *(short4v*)(d +  8) = short4v{ lo8[0], lo8[1], lo8[2], lo8[3] };
        *(short4v*)(d + 12) = short4v{ lo8[4], lo8[5], lo8[6], lo8[7] };
    }
}

// ---------------- tier-2: wlo-only fragment images ----------------
__global__ void precomp_wlo(const float* __restrict__ Wi0, const float* __restrict__ Wi1,
                            float* __restrict__ ws)
{
    const int l = blockIdx.x;
    const float* Wi = l ? Wi1 : Wi0;
    short* wlos = (short*)(ws + 2048) + l*16384;
    int t = threadIdx.x;
    for (int i = 0; i < 8; ++i){
        int slot = i*256 + t;
        int lane = slot & 63, mtks = slot >> 6;
        int mt = mtks >> 1, ks = mtks & 1;
        int g  = (mt << 4) + (lane & 15);
        int k  = (ks << 5) + ((lane >> 4) << 3);
        short tmp[8];
        #pragma unroll
        for (int j = 0; j < 8; ++j){
            float w = Wi[(g << 6) + k + j];
            tmp[j] = bfhi(w - bfhif(w));
        }
        *(short4v*)(wlos + slot*8)     = short4v{ tmp[0], tmp[1], tmp[2], tmp[3] };
        *(short4v*)(wlos + slot*8 + 4) = short4v{ tmp[4], tmp[5], tmp[6], tmp[7] };
    }
}

struct LayerParams { const float *bi, *gi, *addv, *gc, *bc; };

// ---------------- tier-1 kernel: barrier-free, weights fully streamed ----------------
// 256 threads = 4 waves; wave = 16 rows, fully independent. LDS = 16 KB.
// launch_bounds(256,4): 128-reg cap -> 4 waves/SIMD (16 waves/CU). acc[16] = 64
// AGPRs; arch VGPRs must fit in 64 -> gate algebra folded to cut live scalars.
__global__ __launch_bounds__(256, 4) void fwd_nobar(
    const float* __restrict__ x,
    const float* __restrict__ W1, const float* __restrict__ b1,
    const float* __restrict__ g1, const float* __restrict__ be1,
    const float* __restrict__ bi0, const float* __restrict__ gi0,
    const float* __restrict__ gc0, const float* __restrict__ bc0,
    const float* __restrict__ bi1, const float* __restrict__ gi1,
    const float* __restrict__ gc1, const float* __restrict__ bc1,
    const float* __restrict__ Wo, const float* __restrict__ bo,
    const float* __restrict__ ws, float* __restrict__ out, int P)
{
    __shared__ short hb[8192];    // [wave(4)][part(2)][row16][cell64] swizzled (16 KB)

    const int tid  = threadIdx.x;
    const int wid  = tid >> 6;
    const int lane = tid & 63;
    const int c16  = lane & 15;
    const int q    = lane >> 4;
    const int row  = blockIdx.x*64 + wid*16 + c16;
    short* hbw = hb + wid*2048;
    const int swz = (c16 & 7) << 3;
    const short* SB = (const short*)(ws + 2048);

    float xv = 0.0f;
    if (row < P) xv = x[row];
    else if (row == P) xv = ws[0];

    // ---- input layer: h = tanh(LN64(x*W1 + b1)); write per-wave hb ----
    {
        float h[16];
        float sm = 0.f, sq = 0.f;
        #pragma unroll
        for (int mt4 = 0; mt4 < 4; ++mt4){
            const f32x4 w14 = *(const f32x4*)(W1 + mt4*16 + (q << 2));
            const f32x4 b14 = *(const f32x4*)(b1 + mt4*16 + (q << 2));
            #pragma unroll
            for (int r = 0; r < 4; ++r){
                float v = xv*w14[r] + b14[r];
                h[mt4*4+r] = v; sm += v; sq += v*v;
            }
        }
        sm += __shfl_xor(sm, 16); sm += __shfl_xor(sm, 32);
        sq += __shfl_xor(sq, 16); sq += __shfl_xor(sq, 32);
        const float m   = sm * (1.0f/64.0f);
        const float var = (sq - 64.0f*m*m) * (1.0f/63.0f);
        const float inv = frcp(sqrtf(fmaxf(var, 0.0f)) + EPS);
        #pragma unroll
        for (int mt4 = 0; mt4 < 4; ++mt4){
            const f32x4 g14  = *(const f32x4*)(g1  + mt4*16 + (q << 2));
            const f32x4 be14 = *(const f32x4*)(be1 + mt4*16 + (q << 2));
            #pragma unroll
            for (int r = 0; r < 4; ++r)
                h[mt4*4+r] = ftanh((h[mt4*4+r]-m)*inv*g14[r] + be14[r]);
        }
        #pragma unroll
        for (int mt4 = 0; mt4 < 4; ++mt4){
            int si = ((c16 << 6) + mt4*16 + (q << 2)) ^ swz;
            float a = h[mt4*4+0], b = h[mt4*4+1], c = h[mt4*4+2], d = h[mt4*4+3];
            *(short4v*)(hbw + si)        = short4v{ bfhi(a), bfhi(b), bfhi(c), bfhi(d) };
            *(short4v*)(hbw + 1024 + si) = short4v{ bfhi(a-bfhif(a)), bfhi(b-bfhif(b)),
                                                    bfhi(c-bfhif(c)), bfhi(d-bfhif(d)) };
        }
    }
    // no barrier: hb region is private to this wave

    f32x4 acc[16];     // gate accumulators; after do_layer, acc[0..3] = h-out

    auto do_layer = [&](LayerParams p, const short* __restrict__ wfrag, bool writeback){
        bf16x8 bhh[2], bhl[2];
        #pragma unroll
        for (int ks = 0; ks < 2; ++ks){
            int si = ((c16 << 6) + ks*32 + (q << 3)) ^ swz;
            bhh[ks] = *(const bf16x8*)(hbw + si);
            bhl[ks] = *(const bf16x8*)(hbw + 1024 + si);
        }
        #pragma unroll
        for (int mt = 0; mt < 16; ++mt)
            acc[mt] = *(const f32x4*)(p.bi + mt*16 + (q << 2));
        #pragma unroll
        for (int mt = 0; mt < 16; ++mt){
            #pragma unroll
            for (int ks = 0; ks < 2; ++ks){
                int off = (((mt << 1) + ks) << 10) + (lane << 4);   // slot*16 shorts
                bf16x8 whi = *(const bf16x8*)(wfrag + off);
                bf16x8 wlo = *(const bf16x8*)(wfrag + off + 8);
                acc[mt] = __builtin_amdgcn_mfma_f32_16x16x32_bf16(whi, bhh[ks], acc[mt], 0, 0, 0);
                acc[mt] = __builtin_amdgcn_mfma_f32_16x16x32_bf16(whi, bhl[ks], acc[mt], 0, 0, 0);
                acc[mt] = __builtin_amdgcn_mfma_f32_16x16x32_bf16(wlo, bhh[ks], acc[mt], 0, 0, 0);
            }
        }
        // LN256 stats
        float sm = 0.f, sq = 0.f;
        #pragma unroll
        for (int mt = 0; mt < 16; ++mt){
            #pragma unroll
            for (int r = 0; r < 4; ++r){ float v = acc[mt][r]; sm += v; sq += v*v; }
        }
        sm += __shfl_xor(sm, 16); sm += __shfl_xor(sm, 32);
        sq += __shfl_xor(sq, 16); sq += __shfl_xor(sq, 32);
        const float m   = sm * (1.0f/256.0f);
        const float var = (sq - 256.0f*m*m) * (1.0f/255.0f);
        const float inv = frcp(sqrtf(fmaxf(var, 0.0f)) + EPS);

        // gates in place: z_norm = z*t + b with t = inv*gi, b = add - m*t
        // acc[mt4] <- cx = sig(i)*tanh(g); acc[mt4+8] <- o
        #pragma unroll
        for (int mt4 = 0; mt4 < 4; ++mt4){
            #pragma unroll
            for (int r = 0; r < 4; ++r){
                const int c = mt4*16 + (q << 2) + r;
                const float tI = inv * p.gi[      c], bI = p.addv[      c] - m*tI;
                const float tO = inv * p.gi[128 + c], bO = p.addv[128 + c] - m*tO;
                const float tG = inv * p.gi[192 + c], bG = p.addv[192 + c] - m*tG;
                const float i_ = acc[mt4   ][r]*tI + bI;
                const float o_ = acc[mt4+ 8][r]*tO + bO;
                const float g_ = acc[mt4+12][r]*tG + bG;
                acc[mt4   ][r] = fsig(i_) * ftanh(g_);
                acc[mt4+ 8][r] = o_;
            }
        }
        // LN64 over cx (acc[0..3]), then acc[mt4] <- sig(oo)*tanh(LN(cx))
        float s2 = 0.f, q2 = 0.f;
        #pragma unroll
        for (int mt4 = 0; mt4 < 4; ++mt4){
            #pragma unroll
            for (int r = 0; r < 4; ++r){ float v = acc[mt4][r]; s2 += v; q2 += v*v; }
        }
        s2 += __shfl_xor(s2, 16); s2 += __shfl_xor(s2, 32);
        q2 += __shfl_xor(q2, 16); q2 += __shfl_xor(q2, 32);
        const float mc = s2 * (1.0f/64.0f);
        const float vc = (q2 - 64.0f*mc*mc) * (1.0f/63.0f);
        const float ic = frcp(sqrtf(fmaxf(vc, 0.0f)) + EPS);
        #pragma unroll
        for (int mt4 = 0; mt4 < 4; ++mt4){
            #pragma unroll
            for (int r = 0; r < 4; ++r){
                const int c = mt4*16 + (q << 2) + r;
                const float tC = ic * p.gc[c], bC = p.bc[c] - mc*tC;
                acc[mt4][r] = fsig(acc[mt4+8][r]) * ftanh(acc[mt4][r]*tC + bC);
            }
        }
        if (writeback){
            #pragma unroll
            for (int mt4 = 0; mt4 < 4; ++mt4){
                int si = ((c16 << 6) + mt4*16 + (q << 2)) ^ swz;
                float a = acc[mt4][0], b = acc[mt4][1], c = acc[mt4][2], d = acc[mt4][3];
                *(short4v*)(hbw + si)        = short4v{ bfhi(a), bfhi(b), bfhi(c), bfhi(d) };
                *(short4v*)(hbw + 1024 + si) = short4v{ bfhi(a-bfhif(a)), bfhi(b-bfhif(b)),
                                                        bfhi(c-bfhif(c)), bfhi(d-bfhif(d)) };
            }
        }
    };

    do_layer({bi0, gi0, ws + 1056, gc0, bc0}, SB,          true);
    do_layer({bi1, gi1, ws + 1312, gc1, bc1}, SB + 32768, false);

    // output: out = h2 . Wo + bo  (h2 in acc[0..3])
    float o = 0.f;
    #pragma unroll
    for (int mt4 = 0; mt4 < 4; ++mt4){
        const f32x4 wo4 = *(const f32x4*)(Wo + mt4*16 + (q << 2));
        #pragma unroll
        for (int r = 0; r < 4; ++r) o += acc[mt4][r]*wo4[r];
    }
    o += __shfl_xor(o, 16); o += __shfl_xor(o, 32);
    if (q == 0 && row <= P) out[row] = o + bo[0];
}

// ---------------- tier-2 fallback: round-8 proven kernel ----------------
__global__ __launch_bounds__(256, 3) void fwd_stream(
    const float* __restrict__ x,
    const float* __restrict__ W1, const float* __restrict__ b1,
    const float* __restrict__ g1, const float* __restrict__ be1,
    const float* __restrict__ Wi0, const float* __restrict__ bi0,
    const float* __restrict__ gi0, const float* __restrict__ gc0, const float* __restrict__ bc0,
    const float* __restrict__ Wi1, const float* __restrict__ bi1,
    const float* __restrict__ gi1, const float* __restrict__ gc1, const float* __restrict__ bc1,
    const float* __restrict__ Wo, const float* __restrict__ bo,
    const float* __restrict__ ws, float* __restrict__ out, int P)
{
    __shared__ short wl[16384];
    __shared__ short hb[8192];

    const int tid  = threadIdx.x;
    const int wid  = tid >> 6;
    const int lane = tid & 63;
    const int c16  = lane & 15;
    const int q    = lane >> 4;
    const int row  = blockIdx.x*64 + wid*16 + c16;
    short* hbw = hb + wid*2048;
    const int swz = (c16 & 7) << 3;
    const short* SB = (const short*)(ws + 2048);

    auto stage_hi = [&](const float* __restrict__ W){
        #pragma unroll
        for (int i = 0; i < 16; ++i){
            int idx = i*256 + tid;
            int g = idx >> 4, k0 = (idx & 15) << 2;
            f32x4 w4 = *(const f32x4*)(W + (idx << 2));
            int si = ((g << 6) + k0) ^ ((g & 7) << 3);
            *(short4v*)(wl + si) = short4v{ bfhi(w4[0]), bfhi(w4[1]), bfhi(w4[2]), bfhi(w4[3]) };
        }
    };

    stage_hi(Wi0);

    float xv = 0.0f;
    if (row < P) xv = x[row];
    else if (row == P) xv = ws[0];

    {
        float h[16];
        float sm = 0.f, sq = 0.f;
        #pragma unroll
        for (int mt4 = 0; mt4 < 4; ++mt4){
            const f32x4 w14 = *(const f32x4*)(W1 + mt4*16 + (q << 2));
            const f32x4 b14 = *(const f32x4*)(b1 + mt4*16 + (q << 2));
            #pragma unroll
            for (int r = 0; r < 4; ++r){
                float v = xv*w14[r] + b14[r];
                h[mt4*4+r] = v; sm += v; sq += v*v;
            }
        }
        sm += __shfl_xor(sm, 16); sm += __shfl_xor(sm, 32);
        sq += __shfl_xor(sq, 16); sq += __shfl_xor(sq, 32);
        const float m   = sm * (1.0f/64.0f);
        const float var = (sq - 64.0f*m*m) * (1.0f/63.0f);
        const float inv = frcp(sqrtf(fmaxf(var, 0.0f)) + EPS);
        #pragma unroll
        for (int mt4 = 0; mt4 < 4; ++mt4){
            const f32x4 g14  = *(const f32x4*)(g1  + mt4*16 + (q << 2));
            const f32x4 be14 = *(const f32x4*)(be1 + mt4*16 + (q << 2));
            #pragma unroll
            for (int r = 0; r < 4; ++r)
                h[mt4*4+r] = ftanh((h[mt4*4+r]-m)*inv*g14[r] + be14[r]);
        }
        #pragma unroll
        for (int mt4 = 0; mt4 < 4; ++mt4){
            int si = ((c16 << 6) + mt4*16 + (q << 2)) ^ swz;
            float a = h[mt4*4+0], b = h[mt4*4+1], c = h[mt4*4+2], d = h[mt4*4+3];
            *(short4v*)(hbw + si)        = short4v{ bfhi(a), bfhi(b), bfhi(c), bfhi(d) };
            *(short4v*)(hbw + 1024 + si) = short4v{ bfhi(a-bfhif(a)), bfhi(b-bfhif(b)),
                                                    bfhi(c-bfhif(c)), bfhi(d-bfhif(d)) };
        }
    }
    __syncthreads();

    f32x4 acc[16];

    auto do_layer = [&](LayerParams p, const short* __restrict__ wlofrag, bool writeback){
        bf16x8 bhh[2], bhl[2];
        #pragma unroll
        for (int ks = 0; ks < 2; ++ks){
            int si = ((c16 << 6) + ks*32 + (q << 3)) ^ swz;
            bhh[ks] = *(const bf16x8*)(hbw + si);
            bhl[ks] = *(const bf16x8*)(hbw + 1024 + si);
        }
        #pragma unroll
        for (int mt = 0; mt < 16; ++mt)
            acc[mt] = *(const f32x4*)(p.bi + mt*16 + (q << 2));
        #pragma unroll
        for (int mt = 0; mt < 16; ++mt){
            #pragma unroll
            for (int ks = 0; ks < 2; ++ks){
                int si = ((((mt << 4) + c16) << 6) + ks*32 + (q << 3)) ^ swz;
                bf16x8 whi = *(const bf16x8*)(wl + si);
                bf16x8 wlo = *(const bf16x8*)(wlofrag + ((mt*2 + ks) << 9) + (lane << 3));
                acc[mt] = __builtin_amdgcn_mfma_f32_16x16x32_bf16(whi, bhh[ks], acc[mt], 0, 0, 0);
                acc[mt] = __builtin_amdgcn_mfma_f32_16x16x32_bf16(whi, bhl[ks], acc[mt], 0, 0, 0);
                acc[mt] = __builtin_amdgcn_mfma_f32_16x16x32_bf16(wlo, bhh[ks], acc[mt], 0, 0, 0);
            }
        }
        float sm = 0.f, sq = 0.f;
        #pragma unroll
        for (int mt = 0; mt < 16; ++mt){
            #pragma unroll
            for (int r = 0; r < 4; ++r){ float v = acc[mt][r]; sm += v; sq += v*v; }
        }
        sm += __shfl_xor(sm, 16); sm += __shfl_xor(sm, 32);
        sq += __shfl_xor(sq, 16); sq += __shfl_xor(sq, 32);
        const float m   = sm * (1.0f/256.0f);
        const float var = (sq - 256.0f*m*m) * (1.0f/255.0f);
        const float inv = frcp(sqrtf(fmaxf(var, 0.0f)) + EPS);

        #pragma unroll
        for (int mt4 = 0; mt4 < 4; ++mt4){
            #pragma unroll
            for (int r = 0; r < 4; ++r){
                const int c = mt4*16 + (q << 2) + r;
                const float tI = inv * p.gi[      c], bI = p.addv[      c] - m*tI;
                const float tO = inv * p.gi[128 + c], bO = p.addv[128 + c] - m*tO;
                const float tG = inv * p.gi[192 + c], bG = p.addv[192 + c] - m*tG;
                const float i_ = acc[mt4   ][r]*tI + bI;
                const float o_ = acc[mt4+ 8][r]*tO + bO;
                const float g_ = acc[mt4+12][r]*tG + bG;
                acc[mt4   ][r] = fsig(i_) * ftanh(g_);
                acc[mt4+ 8][r] = o_;
            }
        }
        float s2 = 0.f, q2 = 0.f;
        #pragma unroll
        for (int mt4 = 0; mt4 < 4; ++mt4){
            #pragma unroll
            for (int r = 0; r < 4; ++r){ float v = acc[mt4][r]; s2 += v; q2 += v*v; }
        }
        s2 += __shfl_xor(s2, 16); s2 += __shfl_xor(s2, 32);
        q2 += __shfl_xor(q2, 16); q2 += __shfl_xor(q2, 32);
        const float mc = s2 * (1.0f/64.0f);
        const float vc = (q2 - 64.0f*mc*mc) * (1.0f/63.0f);
        const float ic = frcp(sqrtf(fmaxf(vc, 0.0f)) + EPS);
        #pragma unroll
        for (int mt4 = 0; mt4 < 4; ++mt4){
            #pragma unroll
            for (int r = 0; r < 4; ++r){
                const int c = mt4*16 + (q << 2) + r;
                const float tC = ic * p.gc[c], bC = p.bc[c] - mc*tC;
                acc[mt4][r] = fsig(acc[mt4+8][r]) * ftanh(acc[mt4][r]*tC + bC);
            }
        }
        if (writeback){
            #pragma unroll
            for (int mt4 = 0; mt4 < 4; ++mt4){
                int si = ((c16 << 6) + mt4*16 + (q << 2)) ^ swz;
                float a = acc[mt4][0], b = acc[mt4][1], c = acc[mt4][2], d = acc[mt4][3];
                *(short4v*)(hbw + si)        = short4v{ bfhi(a), bfhi(b), bfhi(c), bfhi(d) };
                *(short4v*)(hbw + 1024 + si) = short4v{ bfhi(a-bfhif(a)), bfhi(b-bfhif(b)),
                                                        bfhi(c-bfhif(c)), bfhi(d-bfhif(d)) };
            }
        }
    };

    do_layer({bi0, gi0, ws + 1056, gc0, bc0}, SB,          true);
    __syncthreads();
    stage_hi(Wi1);
    __syncthreads();
    do_layer({bi1, gi1, ws + 1312, gc1, bc1}, SB + 16384, false);

    float o = 0.f;
    #pragma unroll
    for (int mt4 = 0; mt4 < 4; ++mt4){
        const f32x4 wo4 = *(const f32x4*)(Wo + mt4*16 + (q << 2));
        #pragma unroll
        for (int r = 0; r < 4; ++r) o += acc[mt4][r]*wo4[r];
    }
    o += __shfl_xor(o, 16); o += __shfl_xor(o, 32);
    if (q == 0 && row <= P) out[row] = o + bo[0];
}

extern "C" void kernel_launch(void* const* d_in, const int* in_sizes, int n_in,
                              void* d_out, int out_size, void* d_ws, size_t ws_size,
                              hipStream_t stream)
{
    (void)n_in; (void)out_size;
    const float* x     = (const float*)d_in[0];
    const float* W1    = (const float*)d_in[1];
    const float* b1    = (const float*)d_in[2];
    const float* g1    = (const float*)d_in[3];
    const float* be1   = (const float*)d_in[4];
    const float* l0_Wi = (const float*)d_in[5];
    const float* l0_bi = (const float*)d_in[6];
    const float* l0_bh = (const float*)d_in[8];
    const float* l0_gi = (const float*)d_in[9];
    const float* l0_bgi= (const float*)d_in[10];
    const float* l0_gh = (const float*)d_in[11];
    const float* l0_bgh= (const float*)d_in[12];
    const float* l0_gc = (const float*)d_in[13];
    const float* l0_bc = (const float*)d_in[14];
    const float* l1_Wi = (const float*)d_in[15];
    const float* l1_bi = (const float*)d_in[16];
    const float* l1_bh = (const float*)d_in[18];
    const float* l1_gi = (const float*)d_in[19];
    const float* l1_bgi= (const float*)d_in[20];
    const float* l1_gh = (const float*)d_in[21];
    const float* l1_bgh= (const float*)d_in[22];
    const float* l1_gc = (const float*)d_in[23];
    const float* l1_bc = (const float*)d_in[24];
    const float* Wo    = (const float*)d_in[25];
    const float* bo    = (const float*)d_in[26];

    int P = in_sizes[0];
    int B = P + 1;
    float* ws  = (float*)d_ws;
    float* out = (float*)d_out;

    mean_part<<<1024, 256, 0, stream>>>(x, P, ws + 16);
    mean_fin<<<1, 1024, 0, stream>>>(ws + 16, ws, P);
    precomp_add<<<2, 256, 0, stream>>>(
        l0_bh, l0_gh, l0_bgh, l0_bgi,
        l1_bh, l1_gh, l1_bgh, l1_bgi, ws);

    if (ws_size >= (size_t)WS_NEED_FULL){
        precomp_wfrag<<<2, 256, 0, stream>>>(l0_Wi, l1_Wi, ws);
        fwd_nobar<<<(B + 63)/64, 256, 0, stream>>>(
            x, W1, b1, g1, be1,
            l0_bi, l0_gi, l0_gc, l0_bc,
            l1_bi, l1_gi, l1_gc, l1_bc,
            Wo, bo, ws, out, P);
    } else {
        precomp_wlo<<<2, 256, 0, stream>>>(l0_Wi, l1_Wi, ws);
        fwd_stream<<<(B + 63)/64, 256, 0, stream>>>(
            x, W1, b1, g1, be1,
            l0_Wi, l0_bi, l0_gi, l0_gc, l0_bc,
            l1_Wi, l1_bi, l1_gi, l1_gc, l1_bc,
            Wo, bo, ws, out, P);
    }
}